// Round 1
// baseline (100.146 us; speedup 1.0000x reference)
//
#include <hip/hip_runtime.h>
#include <math.h>

#define T 8192
#define D 36
#define NCH 8
#define CHUNK (T / NCH)  // 1024

// ws layout (floats):
// [0,T)      Qp0       [T,2T)   Qp1
// [2T,4T)    Kp interleaved (k0,k1 per j)
// [4T,5T)    Qs0       [5T,6T)  Qs1
// [6T,8T)    Ks interleaved
// [8T,9T)    Vop       [9T,10T) Varg      [10T,11T) Vs
// [11T, 11T+2*T*NCH)            pv (float partial max)
// [11T+2*T*NCH, +2*T*NCH)       pi (int partial argmax)

__global__ __launch_bounds__(256) void proj_kernel(
    const float* __restrict__ E,
    const float* __restrict__ WQp, const float* __restrict__ WKp,
    const float* __restrict__ WVop, const float* __restrict__ WVarg,
    const float* __restrict__ WQs, const float* __restrict__ WKs,
    const float* __restrict__ WVs, float* __restrict__ ws) {
    int t = blockIdx.x * blockDim.x + threadIdx.x;
    if (t >= T) return;
    // row byte offset = t*144, 16B aligned -> 9 float4 loads
    float e[D];
    const float4* Er = (const float4*)(E + t * D);
#pragma unroll
    for (int i = 0; i < D / 4; ++i) {
        float4 v = Er[i];
        e[4 * i + 0] = v.x; e[4 * i + 1] = v.y;
        e[4 * i + 2] = v.z; e[4 * i + 3] = v.w;
    }
    float qp0 = 0.f, qp1 = 0.f, kp0 = 0.f, kp1 = 0.f;
    float qs0 = 0.f, qs1 = 0.f, ks0 = 0.f, ks1 = 0.f;
    float vop = 0.f, varg = 0.f, vs = 0.f;
#pragma unroll
    for (int d = 0; d < D; ++d) {
        float ed = e[d];
        qp0 = fmaf(ed, WQp[d], qp0);
        qp1 = fmaf(ed, WQp[D + d], qp1);
        kp0 = fmaf(ed, WKp[d], kp0);
        kp1 = fmaf(ed, WKp[D + d], kp1);
        qs0 = fmaf(ed, WQs[d], qs0);
        qs1 = fmaf(ed, WQs[D + d], qs1);
        ks0 = fmaf(ed, WKs[d], ks0);
        ks1 = fmaf(ed, WKs[D + d], ks1);
        vop  = fmaf(ed, WVop[d], vop);
        varg = fmaf(ed, WVarg[d], varg);
        vs   = fmaf(ed, WVs[d], vs);
    }
    ws[t]          = qp0;
    ws[T + t]      = qp1;
    ws[2 * T + 2 * t]     = kp0;
    ws[2 * T + 2 * t + 1] = kp1;
    ws[4 * T + t]  = qs0;
    ws[5 * T + t]  = qs1;
    ws[6 * T + 2 * t]     = ks0;
    ws[6 * T + 2 * t + 1] = ks1;
    ws[8 * T + t]  = vop;
    ws[9 * T + t]  = varg;
    ws[10 * T + t] = vs;
}

// grid: (T/256 row-blocks, NCH chunks, 2 heads), block 256
__global__ __launch_bounds__(256) void argmax_kernel(
    const float* __restrict__ wsf, float* __restrict__ pv, int* __restrict__ pi) {
    const int head = blockIdx.z;
    const float* Q0 = wsf + (head ? 4 * T : 0);
    const float* Q1 = Q0 + T;
    const float2* K = (const float2*)(wsf + (head ? 6 * T : 2 * T));

    __shared__ float2 sk[CHUNK];
    const int j0 = blockIdx.y * CHUNK;
    for (int k = threadIdx.x; k < CHUNK; k += 256) sk[k] = K[j0 + k];
    __syncthreads();

    const int row = blockIdx.x * 256 + threadIdx.x;
    const float q0 = Q0[row], q1 = Q1[row];
    float best = -INFINITY;
    int bi = 0;
#pragma unroll 8
    for (int k = 0; k < CHUNK; ++k) {
        float2 kk = sk[k];
        float s = fmaf(q0, kk.x, q1 * kk.y);
        bool gt = s > best;          // strict > keeps first occurrence
        best = gt ? s : best;
        bi   = gt ? k : bi;
    }
    const int prow = head * T + row;
    pv[prow * NCH + blockIdx.y] = best;
    pi[prow * NCH + blockIdx.y] = j0 + bi;
}

__global__ __launch_bounds__(256) void finalize_kernel(
    const float* __restrict__ wsf, const float* __restrict__ pv,
    const int* __restrict__ pi, float* __restrict__ out) {
    int idx = blockIdx.x * blockDim.x + threadIdx.x;  // 0 .. 2T-1
    if (idx >= 2 * T) return;
    const int head = idx >> 13;        // idx / T
    const int row  = idx & (T - 1);
    float best = -INFINITY;
    int bi = 0;
#pragma unroll
    for (int c = 0; c < NCH; ++c) {    // ascending chunk order => first occurrence
        float v = pv[idx * NCH + c];
        int   i2 = pi[idx * NCH + c];
        bool gt = v > best;
        best = gt ? v : best;
        bi   = gt ? i2 : bi;
    }
    const float* Vop  = wsf + 8 * T;
    const float* Varg = wsf + 9 * T;
    const float* Vs   = wsf + 10 * T;
    if (head == 0) {
        out[row]     = Vop[bi];
        out[T + row] = Varg[bi];
    } else {
        out[2 * T + row] = Vs[bi];
    }
}

extern "C" void kernel_launch(void* const* d_in, const int* in_sizes, int n_in,
                              void* d_out, int out_size, void* d_ws, size_t ws_size,
                              hipStream_t stream) {
    const float* E     = (const float*)d_in[0];
    const float* WQp   = (const float*)d_in[1];
    const float* WKp   = (const float*)d_in[2];
    const float* WVop  = (const float*)d_in[3];
    const float* WVarg = (const float*)d_in[4];
    const float* WQs   = (const float*)d_in[5];
    const float* WKs   = (const float*)d_in[6];
    const float* WVs   = (const float*)d_in[7];
    float* out = (float*)d_out;

    float* wsf = (float*)d_ws;
    float* pv  = wsf + 11 * T;
    int*   pi  = (int*)(wsf + 11 * T + 2 * T * NCH);

    proj_kernel<<<T / 256, 256, 0, stream>>>(E, WQp, WKp, WVop, WVarg, WQs, WKs, WVs, wsf);

    dim3 gB(T / 256, NCH, 2);
    argmax_kernel<<<gB, 256, 0, stream>>>(wsf, pv, pi);

    finalize_kernel<<<(2 * T) / 256, 256, 0, stream>>>(wsf, pv, pi, out);
}